// Round 9
// baseline (583.362 us; speedup 1.0000x reference)
//
#include <hip/hip_runtime.h>
#include <hip/hip_bf16.h>

typedef __hip_bfloat16 bf16;
typedef __attribute__((ext_vector_type(8))) short short8;
typedef __attribute__((ext_vector_type(4))) float floatx4;

#define Bn 8
#define Cc 128
#define Hh 128
#define Wl 128
#define HW (Hh*Wl)
#define NT (Bn*HW)   // 131072 tokens
#define REG 8388608  // elements per qkv phase-buffer
#define SC2 0.36067376022224085f   // 0.25 * log2(e)

__device__ __forceinline__ float b2f(bf16 v){ return __bfloat162float(v); }
__device__ __forceinline__ bf16  f2b(float v){ return __float2bfloat16(v); }

// ---------------- all weight transposes in one launch ----------------
__global__ __launch_bounds__(256) void transpose_all(const float* __restrict__ wqkv,
                                                     const float* __restrict__ proj_w,
                                                     const float* __restrict__ fc1_w,
                                                     const float* __restrict__ fc2_w,
                                                     bf16* __restrict__ qkvT,
                                                     bf16* __restrict__ projT,
                                                     bf16* __restrict__ fc1T,
                                                     bf16* __restrict__ fc2T){
  int idx = blockIdx.x*256 + threadIdx.x;
  const float* src; bf16* dst; int K, N;
  if(idx < 49152){ src=wqkv; dst=qkvT; K=128; N=384; }
  else if(idx < 65536){ idx -= 49152; src=proj_w; dst=projT; K=128; N=128; }
  else if(idx < 131072){ idx -= 65536; src=fc1_w; dst=fc1T; K=128; N=512; }
  else { idx -= 131072; src=fc2_w; dst=fc2T; K=512; N=128; }
  int n = idx % N, k = idx / N;
  dst[(size_t)n*K + k] = f2b(src[idx]);
}

// ---------------- depthwise 3x3 conv + bias + residual -> channel-last fp32 ----------------
__global__ __launch_bounds__(256) void conv_kernel(const float* __restrict__ x,
                                                   const float* __restrict__ cw,
                                                   const float* __restrict__ cb,
                                                   float* __restrict__ xt){
  __shared__ float tile[16][132];
  int blk = blockIdx.x;              // ((b*8 + cg)*128 + h)
  int h = blk & 127; int t = blk >> 7;
  int cg = t & 7;    int b = t >> 3;
  int w4 = threadIdx.x & 31;
  int ci = threadIdx.x >> 5;
  int w0 = w4*4;
#pragma unroll
  for(int cc=0; cc<2; cc++){
    int c = cg*16 + ci*2 + cc;
    const float* xp = x + ((size_t)(b*Cc + c))*HW;
    float wg[9];
#pragma unroll
    for(int i=0;i<9;i++) wg[i] = cw[c*9+i];
    float4 rowv[3]; float lf[3], rt[3];
#pragma unroll
    for(int r=0;r<3;r++){
      int hh = h-1+r;
      float4 v = {0.f,0.f,0.f,0.f};
      if(hh>=0 && hh<Hh) v = *(const float4*)(xp + hh*Wl + w0);
      rowv[r] = v;
      float l = __shfl_up(v.w, 1, 32);
      float rr = __shfl_down(v.x, 1, 32);
      lf[r] = (w4==0)  ? 0.f : l;
      rt[r] = (w4==31) ? 0.f : rr;
    }
    float acc0 = cb[c], acc1 = cb[c], acc2 = cb[c], acc3 = cb[c];
#pragma unroll
    for(int r=0;r<3;r++){
      float4 v = rowv[r];
      acc0 += wg[r*3+0]*lf[r] + wg[r*3+1]*v.x + wg[r*3+2]*v.y;
      acc1 += wg[r*3+0]*v.x   + wg[r*3+1]*v.y + wg[r*3+2]*v.z;
      acc2 += wg[r*3+0]*v.y   + wg[r*3+1]*v.z + wg[r*3+2]*v.w;
      acc3 += wg[r*3+0]*v.z   + wg[r*3+1]*v.w + wg[r*3+2]*rt[r];
    }
    acc0 += rowv[1].x; acc1 += rowv[1].y; acc2 += rowv[1].z; acc3 += rowv[1].w;
    float4 o = {acc0, acc1, acc2, acc3};
    *(float4*)&tile[ci*2+cc][w0] = o;
  }
  __syncthreads();
  const size_t obase = ((size_t)b*HW + (size_t)h*Wl)*Cc + cg*16;
#pragma unroll
  for(int i=0;i<8;i++){
    int idx = i*256 + threadIdx.x;
    int c2 = idx & 15, w2 = idx >> 4;
    xt[obase + (size_t)w2*Cc + c2] = tile[c2][w2];
  }
}

// ---------------- LayerNorm over C=128, one wave per token ----------------
__global__ __launch_bounds__(256) void ln_kernel(const float* __restrict__ xt,
                                                 const float* __restrict__ wv,
                                                 const float* __restrict__ bv,
                                                 bf16* __restrict__ xn){
  int tok  = blockIdx.x*4 + (threadIdx.x>>6);
  int lane = threadIdx.x & 63;
  const float* row = xt + (size_t)tok*Cc;
  float v0 = row[lane], v1 = row[lane+64];
  float s = v0+v1;
#pragma unroll
  for(int off=32; off; off>>=1) s += __shfl_down(s, off, 64);
  s = __shfl(s, 0, 64);
  float m = s * (1.0f/128.0f);
  float d0 = v0-m, d1 = v1-m;
  float vs = d0*d0 + d1*d1;
#pragma unroll
  for(int off=32; off; off>>=1) vs += __shfl_down(vs, off, 64);
  vs = __shfl(vs, 0, 64);
  float rstd = rsqrtf(vs*(1.0f/128.0f) + 1e-5f);
  bf16* orow = xn + (size_t)tok*Cc;
  orow[lane]    = f2b(d0*rstd*wv[lane]    + bv[lane]);
  orow[lane+64] = f2b(d1*rstd*wv[lane+64] + bv[lane+64]);
}

// ---------------- MFMA bf16 GEMM, 128x128 tile ----------------
// EPI 0: qkv -> scatter into 6 head-major attention buffers (V stored transposed)
// EPI 1: +bias, GELU, bf16; EPI 2: +bias, xt += ls*v; EPI 3: +bias, bf16(xt + ls*v)
template<int EPI>
__global__ __launch_bounds__(256) void mfma_gemm(const bf16* __restrict__ A,
                                                 const bf16* __restrict__ Wt,
                                                 const float* __restrict__ bias,
                                                 bf16* __restrict__ outb,
                                                 float* __restrict__ xt,
                                                 const float* __restrict__ ls,
                                                 int N, int K){
  __shared__ short As[128*32];   // fragment-order [mtile8][quad4][m16][8]
  __shared__ short Bs[128*32];
  const int m0 = blockIdx.y*128, n0 = blockIdx.x*128;
  const int tid = threadIdx.x;
  const int lane = tid & 63;
  const int w = tid >> 6;

  floatx4 acc[4][4];
#pragma unroll
  for(int i=0;i<4;i++)
#pragma unroll
    for(int j=0;j<4;j++) acc[i][j] = (floatx4){0.f,0.f,0.f,0.f};

  for(int k0=0; k0<K; k0+=32){
#pragma unroll
    for(int p=0;p<2;p++){
      int ch = tid + p*256;
      int r = ch & 127, c = ch >> 7;
      short8 v = *(const short8*)(A + (size_t)(m0+r)*K + k0 + c*8);
      int lidx = ((r>>4)*4 + c)*16 + (r&15);
      *(short8*)&As[lidx*8] = v;
    }
#pragma unroll
    for(int p=0;p<2;p++){
      int ch = tid + p*256;
      int r = ch & 127, c = ch >> 7;
      short8 v = *(const short8*)(Wt + (size_t)(n0+r)*K + k0 + c*8);
      int lidx = ((r>>4)*4 + c)*16 + (r&15);
      *(short8*)&Bs[lidx*8] = v;
    }
    __syncthreads();
    short8 af[4], bfr[4];
#pragma unroll
    for(int mt=0;mt<4;mt++) af[mt]  = *(short8*)&As[(((w&1)*4+mt)*64 + lane)*8];
#pragma unroll
    for(int nt=0;nt<4;nt++) bfr[nt] = *(short8*)&Bs[(((w>>1)*4+nt)*64 + lane)*8];
#pragma unroll
    for(int mt=0;mt<4;mt++)
#pragma unroll
      for(int nt=0;nt<4;nt++)
        acc[mt][nt] = __builtin_amdgcn_mfma_f32_16x16x32_bf16(af[mt], bfr[nt], acc[mt][nt], 0, 0, 0);
    __syncthreads();
  }

  const int n16 = lane & 15, quad = lane >> 4;
#pragma unroll
  for(int mt=0;mt<4;mt++){
#pragma unroll
    for(int nt=0;nt<4;nt++){
#pragma unroll
      for(int r=0;r<4;r++){
        int row = m0 + (w&1)*64 + mt*16 + quad*4 + r;
        int col = n0 + (w>>1)*64 + nt*16 + n16;
        float v = acc[mt][nt][r];
        if(EPI==0){
          // scatter: reg 0..5 = qL,qG,kL,kG,vL,vG  (V transposed: [inst][ch][tok])
          int reg = col >> 6;
          int head = (col >> 4) & 3;
          int ch = col & 15;
          int b = row >> 14, h = (row >> 7) & 127, ww = row & 127;
          size_t didx;
          if(!(reg & 1)){
            int inst = ((b*16 + (h>>3))*16 + (ww>>3))*4 + head;
            int pos = (h&7)*8 + (ww&7);
            didx = (reg==4) ? ((size_t)inst*16 + ch)*64 + pos
                            : ((size_t)inst*64 + pos)*16 + ch;
          } else {
            int inst = ((b*8 + (h&7))*8 + (ww&7))*4 + head;
            int pos = (h>>3)*16 + (ww>>3);
            didx = (reg==5) ? ((size_t)inst*16 + ch)*256 + pos
                            : ((size_t)inst*256 + pos)*16 + ch;
          }
          outb[(size_t)reg*REG + didx] = f2b(v);
        } else if(EPI==1){
          v += bias[col];
          v = 0.5f*v*(1.0f + erff(v*0.70710678118f));
          outb[(size_t)row*N + col] = f2b(v);
        } else if(EPI==2){
          v += bias[col];
          xt[(size_t)row*128 + col] += ls[col]*v;
        } else {
          v += bias[col];
          float rr = xt[(size_t)row*128 + col] + ls[col]*v;
          outb[(size_t)row*128 + col] = f2b(rr);
        }
      }
    }
  }
}

// ---------------- grid attention: online softmax, one Q-tile per wave ----------------
// unit u = blockIdx.x*4 + wave: qt = u&3, inst0 = u>>2 (= ((b*8+si)*8+sj)*4+head)
__global__ __launch_bounds__(256) void attn_grid4(const bf16* __restrict__ qG,
                                                  const bf16* __restrict__ kG,
                                                  const bf16* __restrict__ vG,
                                                  bf16* __restrict__ a){
  __shared__ short pb[4][16*68];   // per-wave P tile (16 q x 64 tok, stride 68)
  const int tid = threadIdx.x;
  const int w = tid >> 6, lane = tid & 63;
  const int n16 = lane & 15, quad = lane >> 4;
  const int u = blockIdx.x*4 + w;
  const int qt = u & 3;
  const int inst0 = u >> 2;
  const int head = inst0 & 3, sj = (inst0>>2)&7, si = (inst0>>5)&7, b = inst0>>8;
  const bf16* Qb = qG + (size_t)inst0*4096;
  const bf16* Kb = kG + (size_t)inst0*4096;
  const bf16* Vb = vG + (size_t)inst0*4096;   // [16 ch][256 tok]
  short* pbw = &pb[w][0];

  short8 qf = {0,0,0,0,0,0,0,0};
  if(quad < 2) qf = *(const short8*)(Qb + (qt*16+n16)*16 + quad*8);

  float m_[4], l_[4];
#pragma unroll
  for(int r=0;r<4;r++){ m_[r] = -1e30f; l_[r] = 0.f; }
  floatx4 of = (floatx4){0.f,0.f,0.f,0.f};

#pragma unroll
  for(int chunk=0; chunk<4; chunk++){
    short8 kf[4];
#pragma unroll
    for(int kt=0;kt<4;kt++){
      short8 v = {0,0,0,0,0,0,0,0};
      if(quad < 2) v = *(const short8*)(Kb + (chunk*64 + kt*16 + n16)*16 + quad*8);
      kf[kt] = v;
    }
    floatx4 sf[4];
#pragma unroll
    for(int kt=0;kt<4;kt++){
      floatx4 z = (floatx4){0.f,0.f,0.f,0.f};
      sf[kt] = __builtin_amdgcn_mfma_f32_16x16x32_bf16(qf, kf[kt], z, 0, 0, 0);
    }
    // chunk row max
    float cm[4];
#pragma unroll
    for(int r=0;r<4;r++){
      cm[r] = fmaxf(fmaxf(sf[0][r], sf[1][r]), fmaxf(sf[2][r], sf[3][r]));
      cm[r] = fmaxf(cm[r], __shfl_xor(cm[r], 1, 64));
      cm[r] = fmaxf(cm[r], __shfl_xor(cm[r], 2, 64));
      cm[r] = fmaxf(cm[r], __shfl_xor(cm[r], 4, 64));
      cm[r] = fmaxf(cm[r], __shfl_xor(cm[r], 8, 64));
    }
    float nms[4], corr[4], ps[4];
#pragma unroll
    for(int r=0;r<4;r++){
      float nm = fmaxf(m_[r], cm[r]);
      corr[r] = exp2f((m_[r] - nm)*SC2);
      m_[r] = nm;
      nms[r] = nm*SC2;
      ps[r] = 0.f;
    }
#pragma unroll
    for(int kt=0;kt<4;kt++){
#pragma unroll
      for(int r=0;r<4;r++){
        float p = exp2f(__fmaf_rn(sf[kt][r], SC2, -nms[r]));
        ps[r] += p;
        bf16 pbv = f2b(p);
        pbw[(quad*4+r)*68 + kt*16 + n16] = *(short*)&pbv;
      }
    }
#pragma unroll
    for(int r=0;r<4;r++){
      ps[r] += __shfl_xor(ps[r], 1, 64);
      ps[r] += __shfl_xor(ps[r], 2, 64);
      ps[r] += __shfl_xor(ps[r], 4, 64);
      ps[r] += __shfl_xor(ps[r], 8, 64);
      l_[r] = l_[r]*corr[r] + ps[r];
      of[r] *= corr[r];
    }
    short8 pf0 = *(short8*)&pbw[n16*68 + quad*8];
    short8 pf1 = *(short8*)&pbw[n16*68 + 32 + quad*8];
    short8 vf0 = *(const short8*)(Vb + n16*256 + chunk*64 + quad*8);
    short8 vf1 = *(const short8*)(Vb + n16*256 + chunk*64 + 32 + quad*8);
    of = __builtin_amdgcn_mfma_f32_16x16x32_bf16(pf0, vf0, of, 0, 0, 0);
    of = __builtin_amdgcn_mfma_f32_16x16x32_bf16(pf1, vf1, of, 0, 0, 0);
  }

  const int ooff = 64 + head*16;
#pragma unroll
  for(int r=0;r<4;r++){
    int pos = qt*16 + quad*4 + r;
    int h = (pos>>4)*8 + si, ww = (pos&15)*8 + sj;
    size_t t = (size_t)b*HW + (size_t)h*Wl + ww;
    a[t*Cc + ooff + n16] = f2b(of[r] / l_[r]);
  }
}

// ---------------- local attention: one Q-tile per wave, L=64 single pass ----------------
__global__ __launch_bounds__(256) void attn_local4(const bf16* __restrict__ qL,
                                                   const bf16* __restrict__ kL,
                                                   const bf16* __restrict__ vL,
                                                   bf16* __restrict__ a){
  __shared__ short pb[4][16*68];
  const int tid = threadIdx.x;
  const int w = tid >> 6, lane = tid & 63;
  const int n16 = lane & 15, quad = lane >> 4;
  const int u = blockIdx.x*4 + w;
  const int qt = u & 3;
  const int inst0 = u >> 2;
  const int head = inst0 & 3, wj = (inst0>>2)&15, wi = (inst0>>6)&15, b = inst0>>10;
  const bf16* Qb = qL + (size_t)inst0*1024;
  const bf16* Kb = kL + (size_t)inst0*1024;
  const bf16* Vb = vL + (size_t)inst0*1024;   // [16 ch][64 tok]
  short* pbw = &pb[w][0];

  short8 qf = {0,0,0,0,0,0,0,0};
  if(quad < 2) qf = *(const short8*)(Qb + (qt*16+n16)*16 + quad*8);

  short8 kf[4];
#pragma unroll
  for(int kt=0;kt<4;kt++){
    short8 v = {0,0,0,0,0,0,0,0};
    if(quad < 2) v = *(const short8*)(Kb + (kt*16 + n16)*16 + quad*8);
    kf[kt] = v;
  }
  floatx4 sf[4];
#pragma unroll
  for(int kt=0;kt<4;kt++){
    floatx4 z = (floatx4){0.f,0.f,0.f,0.f};
    sf[kt] = __builtin_amdgcn_mfma_f32_16x16x32_bf16(qf, kf[kt], z, 0, 0, 0);
  }
  float nms[4], l_[4];
#pragma unroll
  for(int r=0;r<4;r++){
    float cm = fmaxf(fmaxf(sf[0][r], sf[1][r]), fmaxf(sf[2][r], sf[3][r]));
    cm = fmaxf(cm, __shfl_xor(cm, 1, 64));
    cm = fmaxf(cm, __shfl_xor(cm, 2, 64));
    cm = fmaxf(cm, __shfl_xor(cm, 4, 64));
    cm = fmaxf(cm, __shfl_xor(cm, 8, 64));
    nms[r] = cm*SC2;
    l_[r] = 0.f;
  }
#pragma unroll
  for(int kt=0;kt<4;kt++){
#pragma unroll
    for(int r=0;r<4;r++){
      float p = exp2f(__fmaf_rn(sf[kt][r], SC2, -nms[r]));
      l_[r] += p;
      bf16 pbv = f2b(p);
      pbw[(quad*4+r)*68 + kt*16 + n16] = *(short*)&pbv;
    }
  }
#pragma unroll
  for(int r=0;r<4;r++){
    l_[r] += __shfl_xor(l_[r], 1, 64);
    l_[r] += __shfl_xor(l_[r], 2, 64);
    l_[r] += __shfl_xor(l_[r], 4, 64);
    l_[r] += __shfl_xor(l_[r], 8, 64);
  }
  floatx4 of = (floatx4){0.f,0.f,0.f,0.f};
  short8 pf0 = *(short8*)&pbw[n16*68 + quad*8];
  short8 pf1 = *(short8*)&pbw[n16*68 + 32 + quad*8];
  short8 vf0 = *(const short8*)(Vb + n16*64 + quad*8);
  short8 vf1 = *(const short8*)(Vb + n16*64 + 32 + quad*8);
  of = __builtin_amdgcn_mfma_f32_16x16x32_bf16(pf0, vf0, of, 0, 0, 0);
  of = __builtin_amdgcn_mfma_f32_16x16x32_bf16(pf1, vf1, of, 0, 0, 0);

  const int ooff = head*16;
#pragma unroll
  for(int r=0;r<4;r++){
    int pos = qt*16 + quad*4 + r;
    int h = wi*8 + (pos>>3), ww = wj*8 + (pos&7);
    size_t t = (size_t)b*HW + (size_t)h*Wl + ww;
    a[t*Cc + ooff + n16] = f2b(of[r] / l_[r]);
  }
}

// ---------------- (B, HW, C) -> (B, C, HW) transpose, bf16 -> fp32 out ----------------
__global__ __launch_bounds__(256) void transpose_kernel(const bf16* __restrict__ xf,
                                                        float* __restrict__ out){
  __shared__ bf16 tile[32][33];
  int t0 = blockIdx.x*32, c0 = blockIdx.y*32, b = blockIdx.z;
  int x = threadIdx.x, y = threadIdx.y;   // 32, 8
  const bf16* src = xf + (size_t)b*HW*Cc;
  float* dst = out + (size_t)b*Cc*HW;
#pragma unroll
  for(int i=0;i<4;i++)
    tile[y*4+i][x] = src[(size_t)(t0 + y*4+i)*Cc + c0 + x];
  __syncthreads();
#pragma unroll
  for(int i=0;i<4;i++)
    dst[(size_t)(c0 + y*4+i)*HW + t0 + x] = b2f(tile[x][y*4+i]);
}

extern "C" void kernel_launch(void* const* d_in, const int* in_sizes, int n_in,
                              void* d_out, int out_size, void* d_ws, size_t ws_size,
                              hipStream_t stream) {
  const float* x       = (const float*)d_in[0];
  const float* conv_w  = (const float*)d_in[1];
  const float* conv_b  = (const float*)d_in[2];
  const float* norm1_w = (const float*)d_in[3];
  const float* norm1_b = (const float*)d_in[4];
  const float* wqkv    = (const float*)d_in[5];
  const float* proj_w  = (const float*)d_in[6];
  const float* proj_b  = (const float*)d_in[7];
  const float* norm2_w = (const float*)d_in[8];
  const float* norm2_b = (const float*)d_in[9];
  const float* fc1_w   = (const float*)d_in[10];
  const float* fc1_b   = (const float*)d_in[11];
  const float* fc2_w   = (const float*)d_in[12];
  const float* fc2_b   = (const float*)d_in[13];
  const float* ls1     = (const float*)d_in[14];
  const float* ls2     = (const float*)d_in[15];
  float* out = (float*)d_out;

  char* ws = (char*)d_ws;
  float* xt = (float*)ws;                                        // 64 MiB fp32 residual
  bf16*  sh = (bf16*)(ws + (size_t)NT*Cc*4);                     // 32 MiB: xn -> a -> xn2 -> xt_final
  bf16*  qh = (bf16*)(ws + (size_t)NT*Cc*4 + (size_t)NT*Cc*2);   // 128 MiB: qkv buffers, then h1
  bf16*  wt = (bf16*)(ws + (size_t)NT*Cc*4 + (size_t)NT*Cc*2 + (size_t)NT*512*2);
  bf16* qkvT = wt;            // 384 x 128
  bf16* projT= wt + 49152;    // 128 x 128
  bf16* fc1T = wt + 65536;    // 512 x 128
  bf16* fc2T = wt + 131072;   // 128 x 512

  transpose_all<<<196608/256, 256, 0, stream>>>(wqkv, proj_w, fc1_w, fc2_w,
                                                qkvT, projT, fc1T, fc2T);
  conv_kernel<<<Bn*8*Hh, 256, 0, stream>>>(x, conv_w, conv_b, xt);
  ln_kernel<<<NT/4, 256, 0, stream>>>(xt, norm1_w, norm1_b, sh);
  // qkv GEMM scatters into qL,qG,kL,kG,vL(T),vG(T)
  mfma_gemm<0><<<dim3(3, NT/128), 256, 0, stream>>>(sh, qkvT, nullptr, qh, nullptr, nullptr, 384, 128);
  attn_grid4<<<8192, 256, 0, stream>>>(qh + (size_t)1*REG, qh + (size_t)3*REG, qh + (size_t)5*REG, sh);
  attn_local4<<<8192, 256, 0, stream>>>(qh + (size_t)0*REG, qh + (size_t)2*REG, qh + (size_t)4*REG, sh);
  mfma_gemm<2><<<dim3(1, NT/128), 256, 0, stream>>>(sh, projT, proj_b, nullptr, xt, ls1, 128, 128);
  ln_kernel<<<NT/4, 256, 0, stream>>>(xt, norm2_w, norm2_b, sh);
  mfma_gemm<1><<<dim3(4, NT/128), 256, 0, stream>>>(sh, fc1T, fc1_b, qh, nullptr, nullptr, 512, 128);
  mfma_gemm<3><<<dim3(1, NT/128), 256, 0, stream>>>(qh, fc2T, fc2_b, sh, xt, ls2, 128, 512);
  transpose_kernel<<<dim3(HW/32, Cc/32, Bn), dim3(32,8), 0, stream>>>(sh, out);
}